// Round 1
// 955.713 us; speedup vs baseline: 1.1700x; 1.1700x over previous
//
#include <hip/hip_runtime.h>

// Problem constants (B,S,D,H fixed by the reference)
#define Bb 8
#define Ss 1024
#define Dd 1024
#define Hh 16
#define DEPTHh 64
#define BSD (Bb*Ss*Dd)          // 8388608
#define DDn (Dd*Dd)             // 1048576

typedef __bf16 bf16x8 __attribute__((ext_vector_type(8)));
typedef float  f32x4  __attribute__((ext_vector_type(4)));

__device__ __forceinline__ unsigned short f2bf(float f){
  unsigned u = __float_as_uint(f);
  u = (u + 0x7fffu + ((u >> 16) & 1u)) >> 16;   // RNE
  return (unsigned short)u;
}
__device__ __forceinline__ float bf2f(unsigned short h){
  return __uint_as_float(((unsigned)h) << 16);
}

// ---------------- elementwise fp32 -> bf16 convert ----------------
__global__ __launch_bounds__(256) void cvt_bf16(const float4* __restrict__ in,
                                                ushort4* __restrict__ out, int n4){
  int i = blockIdx.x*256 + threadIdx.x;
  if (i >= n4) return;
  float4 v = in[i];
  ushort4 o; o.x = f2bf(v.x); o.y = f2bf(v.y); o.z = f2bf(v.z); o.w = f2bf(v.w);
  out[i] = o;
}

// ---------------- W [D,D] fp32 -> W^T [D,D] bf16 ----------------
__global__ __launch_bounds__(256) void transpose_w(const float* __restrict__ W,
                                                   ushort* __restrict__ WT){
  __shared__ float tl[32][33];
  int tx = threadIdx.x, ty = threadIdx.y;        // block (32,8)
  int bx = blockIdx.x*32, by = blockIdx.y*32;
  #pragma unroll
  for (int i=0;i<32;i+=8) tl[ty+i][tx] = W[(by+ty+i)*Dd + bx+tx];
  __syncthreads();
  #pragma unroll
  for (int i=0;i<32;i+=8) WT[(bx+ty+i)*Dd + by+tx] = f2bf(tl[tx][ty+i]);
}

// ---------------- vh [bh,s,64] -> vt [bh,64,s] (bf16) ----------------
__global__ __launch_bounds__(512) void transpose_v(const ushort* __restrict__ vh,
                                                   ushort* __restrict__ vt){
  __shared__ ushort tl[64][65];
  int tx = threadIdx.x, ty = threadIdx.y;        // block (64,8)
  long base = (long)blockIdx.y * 65536;          // bh * S*depth
  int s0 = blockIdx.x*64;
  #pragma unroll
  for (int i=0;i<64;i+=8) tl[ty+i][tx] = vh[base + (long)(s0+ty+i)*64 + tx];
  __syncthreads();
  #pragma unroll
  for (int i=0;i<64;i+=8) vt[base + (long)(ty+i)*1024 + s0 + tx] = tl[tx][ty+i];
}

// ---------------- BT-GEMM: C[m,n] = sum_k A[m,k]*B[n,k], bf16 MFMA ----------------
// 64x64 tile, 4 waves in 2x2 arrangement, each wave 2x2 of 16x16x32 MFMA tiles.
// Kept for the 4 dense [8192x1024]@[1024x1024] GEMMs (proj x3 + final).
enum { M_PROJ=0, M_FINAL=3 };

template<int MODE>
__global__ __launch_bounds__(256) void gemm_bt(
    const ushort* __restrict__ Aall, const ushort* __restrict__ Ball,
    int lda, int ldb, int K, long sA, long sB,
    float* __restrict__ outf, ushort* __restrict__ outh,
    const float* __restrict__ aux)
{
  __shared__ ushort As[64][40];   // +8 pad: 80B row stride, 16B-aligned, ~2-way banks (free)
  __shared__ ushort Bs[64][40];
  const int z = blockIdx.z;
  const ushort* A  = Aall + (long)z*sA;
  const ushort* Bp = Ball + (long)z*sB;
  const int m0 = blockIdx.x*64, n0 = blockIdx.y*64;
  const int t = threadIdx.x;
  const int lane = t & 63, wave = t >> 6;
  const int wm = (wave>>1)*32, wn = (wave&1)*32;
  const int q = lane>>4, l16 = lane&15;
  const int srow = t>>2, scol = (t&3)*8;         // staging: 8 bf16 (16B) per thread

  f32x4 acc[2][2] = {};

  for (int k0=0; k0<K; k0+=32){
    uint4 av = *(const uint4*)(A  + (long)(m0+srow)*lda + k0 + scol);
    uint4 bv = *(const uint4*)(Bp + (long)(n0+srow)*ldb + k0 + scol);
    __syncthreads();
    *(uint4*)(&As[srow][scol]) = av;
    *(uint4*)(&Bs[srow][scol]) = bv;
    __syncthreads();
    bf16x8 a0 = *(const bf16x8*)(&As[wm      + l16][q*8]);
    bf16x8 a1 = *(const bf16x8*)(&As[wm + 16 + l16][q*8]);
    bf16x8 b0 = *(const bf16x8*)(&Bs[wn      + l16][q*8]);
    bf16x8 b1 = *(const bf16x8*)(&Bs[wn + 16 + l16][q*8]);
    acc[0][0] = __builtin_amdgcn_mfma_f32_16x16x32_bf16(a0,b0,acc[0][0],0,0,0);
    acc[0][1] = __builtin_amdgcn_mfma_f32_16x16x32_bf16(a0,b1,acc[0][1],0,0,0);
    acc[1][0] = __builtin_amdgcn_mfma_f32_16x16x32_bf16(a1,b0,acc[1][0],0,0,0);
    acc[1][1] = __builtin_amdgcn_mfma_f32_16x16x32_bf16(a1,b1,acc[1][1],0,0,0);
  }

  // C/D layout (m89/m91 verified): col = lane&15, row = (lane>>4)*4 + reg
  #pragma unroll
  for (int ti=0; ti<2; ti++)
  #pragma unroll
  for (int tj=0; tj<2; tj++)
  #pragma unroll
  for (int r=0; r<4; r++){
    float v = acc[ti][tj][r];
    const int row = m0 + wm + ti*16 + q*4 + r;
    const int col = n0 + wn + tj*16 + l16;
    if (MODE == M_PROJ){
      // row = b*S+s over [B*S, D]; write head-split [b,h,s,d] bf16
      v += aux[col];
      const int b = row>>10, s = row&1023, h = col>>6, d = col&63;
      outh[((long)((b*Hh + h)*Ss + s)<<6) + d] = f2bf(v);
    } else { // M_FINAL
      v += aux[col];
      outf[(long)row*Dd + col] = v;
    }
  }
}

// ---------------- fused scores + softmax + PV ----------------
// One block = one (b,h) x 64 q-rows. Two-pass flash:
//   pass 1: per 64-key strip, QK^T (bf16 MFMA) -> per-lane online (m,l)
//           (branchless rescale; exact after lane16-xor + wave-pair LDS combine)
//   pass 2: recompute QK^T, p = exp(s*0.125+mask-m)/l,
//           write fp32 attn (mandatory output) directly,
//           round-trip p->bf16 via LDS (gives A-frag layout AND exchanges the
//           two col-wave halves), accumulate PV into registers.
// Eliminates bf16 scores write+read and bf16 attn write+read (~1.0 GB HBM).
__global__ __launch_bounds__(256) void attn_fused(
    const ushort* __restrict__ qh,   // [z][1024][64] bf16
    const ushort* __restrict__ kh,   // [z][1024][64] bf16
    const ushort* __restrict__ vt,   // [z][64][1024] bf16 (v^T)
    const float*  __restrict__ mask, // [B][1024]
    float* __restrict__ attn_f,      // [z][1024][1024] fp32 out
    ushort* __restrict__ concat)     // [b][1024][1024] bf16 (h*64+d cols)
{
  // pad 72: row stride 144B -> 4-bank shift/row -> 2-way b128 conflicts (free, m136)
  __shared__ __align__(16) ushort qs[64][72];
  __shared__ __align__(16) ushort ks[64][72];
  __shared__ __align__(16) ushort vs[64][72];
  __shared__ __align__(16) ushort ps[64][72];
  __shared__ float red_m[2][64];
  __shared__ float red_l[2][64];

  const int z = blockIdx.z;             // b*H + h
  const int b = z >> 4, h = z & 15;
  const int t = threadIdx.x;
  const int lane = t & 63, wave = t >> 6;
  const int wm = (wave >> 1) * 32;      // row half this wave owns
  const int wc = wave & 1;              // col-wave (key-strip half / d half)
  const int wn = wc * 32;
  const int q = lane >> 4, l16 = lane & 15;
  const int srow = t >> 2, sc = (t & 3) * 8;    // staging: row, ushort chunk

  const ushort* qz = qh + ((long)z << 16);
  const ushort* kz = kh + ((long)z << 16);
  const ushort* vz = vt + ((long)z << 16);
  const int q0 = blockIdx.x * 64;       // q-row tile base

  // stage Q tile once (visible after first barrier below)
  {
    const ushort* src = qz + (long)(q0 + srow) * 64 + sc;
    *(uint4*)(&qs[srow][sc])      = *(const uint4*)(src);
    *(uint4*)(&qs[srow][sc + 32]) = *(const uint4*)(src + 32);
  }

  float m_ln[2][4], l_ln[2][4];
  #pragma unroll
  for (int ti=0; ti<2; ti++)
  #pragma unroll
  for (int r=0; r<4; r++){ m_ln[ti][r] = -1e30f; l_ln[ti][r] = 0.f; }

  // ---------------- pass 1: row max + sum ----------------
  for (int s = 0; s < 16; ++s){
    const int k0 = s * 64;
    const ushort* ksrc = kz + (long)(k0 + srow) * 64 + sc;
    uint4 kv0 = *(const uint4*)(ksrc);
    uint4 kv1 = *(const uint4*)(ksrc + 32);
    __syncthreads();
    *(uint4*)(&ks[srow][sc])      = kv0;
    *(uint4*)(&ks[srow][sc + 32]) = kv1;
    __syncthreads();

    f32x4 accs[2][2] = {};
    #pragma unroll
    for (int kk=0; kk<2; ++kk){
      bf16x8 a0 = *(const bf16x8*)(&qs[wm      + l16][kk*32 + q*8]);
      bf16x8 a1 = *(const bf16x8*)(&qs[wm + 16 + l16][kk*32 + q*8]);
      bf16x8 b0 = *(const bf16x8*)(&ks[wn      + l16][kk*32 + q*8]);
      bf16x8 b1 = *(const bf16x8*)(&ks[wn + 16 + l16][kk*32 + q*8]);
      accs[0][0] = __builtin_amdgcn_mfma_f32_16x16x32_bf16(a0,b0,accs[0][0],0,0,0);
      accs[0][1] = __builtin_amdgcn_mfma_f32_16x16x32_bf16(a0,b1,accs[0][1],0,0,0);
      accs[1][0] = __builtin_amdgcn_mfma_f32_16x16x32_bf16(a1,b0,accs[1][0],0,0,0);
      accs[1][1] = __builtin_amdgcn_mfma_f32_16x16x32_bf16(a1,b1,accs[1][1],0,0,0);
    }
    const float mk0 = mask[(b<<10) + k0 + wn + l16]      * (-1e9f);
    const float mk1 = mask[(b<<10) + k0 + wn + 16 + l16] * (-1e9f);
    #pragma unroll
    for (int ti=0; ti<2; ti++)
    #pragma unroll
    for (int r=0; r<4; r++){
      const float s0 = accs[ti][0][r]*0.125f + mk0;
      const float s1 = accs[ti][1][r]*0.125f + mk1;
      const float mn = fmaxf(m_ln[ti][r], fmaxf(s0, s1));
      l_ln[ti][r] = l_ln[ti][r]*__expf(m_ln[ti][r]-mn)
                  + __expf(s0-mn) + __expf(s1-mn);
      m_ln[ti][r] = mn;
    }
  }

  // reduce (m,l) across the 16 l16 lanes (rows live at q*4+r, q untouched by xor<16)
  #pragma unroll
  for (int ti=0; ti<2; ti++)
  #pragma unroll
  for (int r=0; r<4; r++){
    float m = m_ln[ti][r], l = l_ln[ti][r];
    #pragma unroll
    for (int off=1; off<16; off<<=1){
      float om = __shfl_xor(m, off, 64);
      float ol = __shfl_xor(l, off, 64);
      float mn = fmaxf(m, om);
      l = l*__expf(m-mn) + ol*__expf(om-mn);
      m = mn;
    }
    m_ln[ti][r] = m; l_ln[ti][r] = l;
  }
  // combine the two col-waves sharing this row half
  if (l16 == 0){
    #pragma unroll
    for (int ti=0; ti<2; ti++)
    #pragma unroll
    for (int r=0; r<4; r++){
      const int row = wm + ti*16 + q*4 + r;
      red_m[wc][row] = m_ln[ti][r];
      red_l[wc][row] = l_ln[ti][r];
    }
  }
  __syncthreads();
  float m_fin[2][4], li[2][4];
  #pragma unroll
  for (int ti=0; ti<2; ti++)
  #pragma unroll
  for (int r=0; r<4; r++){
    const int row = wm + ti*16 + q*4 + r;
    const float m0 = red_m[0][row], m1 = red_m[1][row];
    const float l0 = red_l[0][row], l1 = red_l[1][row];
    const float mt = fmaxf(m0, m1);
    const float lt = l0*__expf(m0-mt) + l1*__expf(m1-mt);
    m_fin[ti][r] = mt;
    li[ti][r] = 1.0f / lt;
  }

  // ---------------- pass 2: attn write + PV ----------------
  f32x4 accp[2][2] = {};
  for (int s = 0; s < 16; ++s){
    const int k0 = s * 64;
    const ushort* ksrc = kz + (long)(k0 + srow) * 64 + sc;
    const ushort* vsrc = vz + (long)srow * 1024 + k0 + sc;
    uint4 kv0 = *(const uint4*)(ksrc);
    uint4 kv1 = *(const uint4*)(ksrc + 32);
    uint4 vv0 = *(const uint4*)(vsrc);
    uint4 vv1 = *(const uint4*)(vsrc + 32);
    __syncthreads();
    *(uint4*)(&ks[srow][sc])      = kv0;
    *(uint4*)(&ks[srow][sc + 32]) = kv1;
    *(uint4*)(&vs[srow][sc])      = vv0;
    *(uint4*)(&vs[srow][sc + 32]) = vv1;
    __syncthreads();

    f32x4 accs[2][2] = {};
    #pragma unroll
    for (int kk=0; kk<2; ++kk){
      bf16x8 a0 = *(const bf16x8*)(&qs[wm      + l16][kk*32 + q*8]);
      bf16x8 a1 = *(const bf16x8*)(&qs[wm + 16 + l16][kk*32 + q*8]);
      bf16x8 b0 = *(const bf16x8*)(&ks[wn      + l16][kk*32 + q*8]);
      bf16x8 b1 = *(const bf16x8*)(&ks[wn + 16 + l16][kk*32 + q*8]);
      accs[0][0] = __builtin_amdgcn_mfma_f32_16x16x32_bf16(a0,b0,accs[0][0],0,0,0);
      accs[0][1] = __builtin_amdgcn_mfma_f32_16x16x32_bf16(a0,b1,accs[0][1],0,0,0);
      accs[1][0] = __builtin_amdgcn_mfma_f32_16x16x32_bf16(a1,b0,accs[1][0],0,0,0);
      accs[1][1] = __builtin_amdgcn_mfma_f32_16x16x32_bf16(a1,b1,accs[1][1],0,0,0);
    }
    const float mk0 = mask[(b<<10) + k0 + wn + l16]      * (-1e9f);
    const float mk1 = mask[(b<<10) + k0 + wn + 16 + l16] * (-1e9f);
    #pragma unroll
    for (int ti=0; ti<2; ti++)
    #pragma unroll
    for (int r=0; r<4; r++){
      const int row = wm + ti*16 + q*4 + r;
      const float p0 = __expf(accs[ti][0][r]*0.125f + mk0 - m_fin[ti][r]) * li[ti][r];
      const float p1 = __expf(accs[ti][1][r]*0.125f + mk1 - m_fin[ti][r]) * li[ti][r];
      float* arow = attn_f + (((long)z<<20) + ((long)(q0+row)<<10) + k0);
      arow[wn + l16]      = p0;
      arow[wn + 16 + l16] = p1;
      ps[row][wn + l16]      = f2bf(p0);
      ps[row][wn + 16 + l16] = f2bf(p1);
    }
    __syncthreads();
    // PV: A = p[64 rows x 64 keys] (from ps, both halves), B = v^T[d][keys] (vs)
    #pragma unroll
    for (int kk=0; kk<2; ++kk){
      bf16x8 a0 = *(const bf16x8*)(&ps[wm      + l16][kk*32 + q*8]);
      bf16x8 a1 = *(const bf16x8*)(&ps[wm + 16 + l16][kk*32 + q*8]);
      bf16x8 b0 = *(const bf16x8*)(&vs[wn      + l16][kk*32 + q*8]);
      bf16x8 b1 = *(const bf16x8*)(&vs[wn + 16 + l16][kk*32 + q*8]);
      accp[0][0] = __builtin_amdgcn_mfma_f32_16x16x32_bf16(a0,b0,accp[0][0],0,0,0);
      accp[0][1] = __builtin_amdgcn_mfma_f32_16x16x32_bf16(a0,b1,accp[0][1],0,0,0);
      accp[1][0] = __builtin_amdgcn_mfma_f32_16x16x32_bf16(a1,b0,accp[1][0],0,0,0);
      accp[1][1] = __builtin_amdgcn_mfma_f32_16x16x32_bf16(a1,b1,accp[1][1],0,0,0);
    }
  }

  // epilogue: out rows (wm half), d cols (wn half) -> concat [b,s,h*64+d] bf16
  #pragma unroll
  for (int mi=0; mi<2; mi++)
  #pragma unroll
  for (int nj=0; nj<2; nj++)
  #pragma unroll
  for (int r=0; r<4; r++){
    const int row = q0 + wm + mi*16 + q*4 + r;
    const int d   = wn + nj*16 + l16;
    concat[(((long)(b<<10) + row)<<10) + (h<<6) + d] = f2bf(accp[mi][nj][r]);
  }
}

extern "C" void kernel_launch(void* const* d_in, const int* in_sizes, int n_in,
                              void* d_out, int out_size, void* d_ws, size_t ws_size,
                              hipStream_t stream)
{
  (void)in_sizes; (void)n_in; (void)out_size; (void)ws_size;
  const float* Q    = (const float*)d_in[0];
  const float* Kin  = (const float*)d_in[1];
  const float* V    = (const float*)d_in[2];
  const float* mask = (const float*)d_in[3];
  const float* Wq   = (const float*)d_in[4];
  const float* bq   = (const float*)d_in[5];
  const float* Wk   = (const float*)d_in[6];
  const float* bk   = (const float*)d_in[7];
  const float* Wv   = (const float*)d_in[8];
  const float* bv   = (const float*)d_in[9];
  const float* Wo   = (const float*)d_in[10];
  const float* bo   = (const float*)d_in[11];
  float* out    = (float*)d_out;
  float* attn_f = out + (long)BSD;

  // Workspace layout (ushort elements) — unchanged from previous round.
  ushort* ws     = (ushort*)d_ws;
  ushort* Xq     = ws;                 // bf16 Q input; reused as concat buffer later
  ushort* Xk     = Xq  + (long)BSD;
  ushort* Xv     = Xk  + (long)BSD;
  ushort* WqT    = Xv  + (long)BSD;
  ushort* WkT    = WqT + (long)DDn;
  ushort* WvT    = WkT + (long)DDn;
  ushort* WoT    = WvT + (long)DDn;
  ushort* qh     = WoT + (long)DDn;    // [b,h,s,64] bf16
  ushort* kh     = qh  + (long)BSD;
  ushort* vt     = kh  + (long)BSD;    // [b,h,64,s] bf16
  ushort* vh     = vt  + (long)BSD;    // temp [b,h,s,64] (old attn_h region)
  ushort* concat = Xq;                 // [b,s,D] bf16, reuse of Xq

  // 1. fp32 -> bf16 input converts
  cvt_bf16<<<dim3(BSD/4/256), 256, 0, stream>>>((const float4*)Q,   (ushort4*)Xq, BSD/4);
  cvt_bf16<<<dim3(BSD/4/256), 256, 0, stream>>>((const float4*)Kin, (ushort4*)Xk, BSD/4);
  cvt_bf16<<<dim3(BSD/4/256), 256, 0, stream>>>((const float4*)V,   (ushort4*)Xv, BSD/4);

  // 2. weight transposes (fp32 -> bf16 W^T)
  transpose_w<<<dim3(32,32), dim3(32,8), 0, stream>>>(Wq, WqT);
  transpose_w<<<dim3(32,32), dim3(32,8), 0, stream>>>(Wk, WkT);
  transpose_w<<<dim3(32,32), dim3(32,8), 0, stream>>>(Wv, WvT);
  transpose_w<<<dim3(32,32), dim3(32,8), 0, stream>>>(Wo, WoT);

  // 3. projections: [8192,1024] @ W^T -> head-split bf16
  gemm_bt<M_PROJ><<<dim3(128,16,1), 256, 0, stream>>>(Xq, WqT, Dd, Dd, Dd, 0,0, nullptr, qh, bq);
  gemm_bt<M_PROJ><<<dim3(128,16,1), 256, 0, stream>>>(Xk, WkT, Dd, Dd, Dd, 0,0, nullptr, kh, bk);
  gemm_bt<M_PROJ><<<dim3(128,16,1), 256, 0, stream>>>(Xv, WvT, Dd, Dd, Dd, 0,0, nullptr, vh, bv);

  // 3b. v [bh,s,64] -> v^T [bh,64,s]
  transpose_v<<<dim3(16,128), dim3(64,8), 0, stream>>>(vh, vt);

  // 4-6 fused: scores -> softmax (fp32 attn out) -> PV (bf16 concat out)
  attn_fused<<<dim3(16,1,128), 256, 0, stream>>>(qh, kh, vt, mask, attn_f, concat);

  // 7. final: concat @ Wo + bo -> fp32 out
  gemm_bt<M_FINAL><<<dim3(128,16,1), 256, 0, stream>>>(concat, WoT, Dd, Dd, Dd,
                                                       0,0, out, nullptr, bo);
}

// Round 2
// 916.897 us; speedup vs baseline: 1.2195x; 1.0423x over previous
//
#include <hip/hip_runtime.h>

// Problem constants (B,S,D,H fixed by the reference)
#define Bb 8
#define Ss 1024
#define Dd 1024
#define Hh 16
#define BSD (Bb*Ss*Dd)          // 8388608
#define DDn (Dd*Dd)             // 1048576

typedef __bf16 bf16x8 __attribute__((ext_vector_type(8)));
typedef float  f32x4  __attribute__((ext_vector_type(4)));

__device__ __forceinline__ unsigned short f2bf(float f){
  unsigned u = __float_as_uint(f);
  u = (u + 0x7fffu + ((u >> 16) & 1u)) >> 16;   // RNE
  return (unsigned short)u;
}
__device__ __forceinline__ float fexp2(float x){ return __builtin_exp2f(x); }

// async global->LDS, 16B per lane. LDS dest must be wave-uniform base + lane*16.
__device__ __forceinline__ void gload16(const ushort* g, ushort* l){
  __builtin_amdgcn_global_load_lds(
      (const __attribute__((address_space(1))) void*)g,
      (__attribute__((address_space(3))) void*)l, 16, 0, 0);
}

// ---------------- elementwise fp32 -> bf16 convert ----------------
__global__ __launch_bounds__(256) void cvt_bf16(const float4* __restrict__ in,
                                                ushort4* __restrict__ out, int n4){
  int i = blockIdx.x*256 + threadIdx.x;
  if (i >= n4) return;
  float4 v = in[i];
  ushort4 o; o.x = f2bf(v.x); o.y = f2bf(v.y); o.z = f2bf(v.z); o.w = f2bf(v.w);
  out[i] = o;
}

// ---------------- W [D,D] fp32 -> W^T [D,D] bf16 ----------------
__global__ __launch_bounds__(256) void transpose_w(const float* __restrict__ W,
                                                   ushort* __restrict__ WT){
  __shared__ float tl[32][33];
  int tx = threadIdx.x, ty = threadIdx.y;        // block (32,8)
  int bx = blockIdx.x*32, by = blockIdx.y*32;
  #pragma unroll
  for (int i=0;i<32;i+=8) tl[ty+i][tx] = W[(by+ty+i)*Dd + bx+tx];
  __syncthreads();
  #pragma unroll
  for (int i=0;i<32;i+=8) WT[(bx+ty+i)*Dd + by+tx] = f2bf(tl[tx][ty+i]);
}

// ---------------- vh [bh,s,64] -> vt [bh,64,s] (bf16) ----------------
__global__ __launch_bounds__(512) void transpose_v(const ushort* __restrict__ vh,
                                                   ushort* __restrict__ vt){
  __shared__ ushort tl[64][65];
  int tx = threadIdx.x, ty = threadIdx.y;        // block (64,8)
  long base = (long)blockIdx.y * 65536;          // bh * S*depth
  int s0 = blockIdx.x*64;
  #pragma unroll
  for (int i=0;i<64;i+=8) tl[ty+i][tx] = vh[base + (long)(s0+ty+i)*64 + tx];
  __syncthreads();
  #pragma unroll
  for (int i=0;i<64;i+=8) vt[base + (long)(ty+i)*1024 + s0 + tx] = tl[tx][ty+i];
}

// ---------------- 128x128 BT-GEMM (m97 structure): C = A * B^T ----------------
// 4 waves, each 64x64 quadrant (4x4 of 16x16x32 MFMA). global_load_lds w=16,
// linear LDS [128][32] bf16 per operand (8KB each). K = 1024.
enum { M_PROJ=0, M_FINAL=3 };

template<int MODE>
__global__ __launch_bounds__(256) void gemm128(
    const ushort* __restrict__ A, const ushort* __restrict__ B,
    float* __restrict__ outf, ushort* __restrict__ outh,
    const float* __restrict__ aux)
{
  __shared__ __align__(16) ushort As[128*32];
  __shared__ __align__(16) ushort Bs[128*32];
  const int t = threadIdx.x, lane = t & 63, wave = t >> 6;
  const int m0 = blockIdx.x*128, n0 = blockIdx.y*128;
  const int wm = (wave>>1)*64, wn = (wave&1)*64;
  const int q = lane>>4, l16 = lane&15;
  // staging: chunk = round*256 + t ; row = chunk>>2, colchunk = chunk&3 (8 ushorts)
  const int row0 = t>>2, cc = (t&3)*8;

  ushort* lA0 = As + wave*512;          // wave-uniform LDS bases (lane*16B implicit)
  ushort* lA1 = As + 2048 + wave*512;
  ushort* lB0 = Bs + wave*512;
  ushort* lB1 = Bs + 2048 + wave*512;
  const ushort* gA0 = A + (long)(m0+row0)*Dd + cc;
  const ushort* gA1 = A + (long)(m0+row0+64)*Dd + cc;
  const ushort* gB0 = B + (long)(n0+row0)*Dd + cc;
  const ushort* gB1 = B + (long)(n0+row0+64)*Dd + cc;

  f32x4 acc[4][4] = {};

  for (int k0=0; k0<Dd; k0+=32){
    __syncthreads();
    gload16(gA0+k0, lA0);
    gload16(gA1+k0, lA1);
    gload16(gB0+k0, lB0);
    gload16(gB1+k0, lB1);
    __syncthreads();
    bf16x8 af[4], bfr[4];
    #pragma unroll
    for (int i=0;i<4;i++){
      af[i]  = *(const bf16x8*)(As + (wm+i*16+l16)*32 + q*8);
      bfr[i] = *(const bf16x8*)(Bs + (wn+i*16+l16)*32 + q*8);
    }
    #pragma unroll
    for (int mi=0;mi<4;mi++)
    #pragma unroll
    for (int nj=0;nj<4;nj++)
      acc[mi][nj] = __builtin_amdgcn_mfma_f32_16x16x32_bf16(af[mi],bfr[nj],acc[mi][nj],0,0,0);
  }

  // C/D layout: col = lane&15, row = (lane>>4)*4 + reg
  #pragma unroll
  for (int mi=0;mi<4;mi++)
  #pragma unroll
  for (int nj=0;nj<4;nj++)
  #pragma unroll
  for (int r=0;r<4;r++){
    float v = acc[mi][nj][r];
    const int row = m0 + wm + mi*16 + q*4 + r;
    const int col = n0 + wn + nj*16 + l16;
    v += aux[col];
    if (MODE == M_PROJ){
      const int b = row>>10, s = row&1023, h = col>>6, d = col&63;
      outh[((long)((b*Hh + h)*Ss + s)<<6) + d] = f2bf(v);
    } else { // M_FINAL
      outf[(long)row*Dd + col] = v;
    }
  }
}

// ---------------- fused scores + softmax + PV (swapped-QK, exp2 domain) ----------------
// One block = one (b,h) x 64 q-rows. Two-pass exact softmax.
// QK^T is computed SWAPPED: S^T[key][query] = mfma(K,Q), so each thread's 4 acc
// regs are 4 consecutive KEYS of one query -> attn_f writes are float4, ps writes
// are ds_write_b64, and the key-reduction is mostly thread-local.
// All softmax math in log2 domain (scale/mask pre-multiplied by log2e).
__global__ __launch_bounds__(256) void attn_fused(
    const ushort* __restrict__ qh,   // [z][1024][64] bf16
    const ushort* __restrict__ kh,   // [z][1024][64] bf16
    const ushort* __restrict__ vt,   // [z][64][1024] bf16 (v^T)
    const float*  __restrict__ mask, // [B][1024]
    float* __restrict__ attn_f,      // [z][1024][1024] fp32 out
    ushort* __restrict__ concat)     // [b][1024][1024] bf16 (h*64+d cols)
{
  // pad 72: row stride 144B -> 2-way b128 conflicts (free, m136)
  __shared__ __align__(16) ushort qs[64][72];
  __shared__ __align__(16) ushort ks[64][72];
  __shared__ __align__(16) ushort vs[64][72];
  __shared__ __align__(16) ushort ps[64][72];
  __shared__ float msk[64];
  __shared__ float red_m[2][64];
  __shared__ float red_l[2][64];

  const int z = blockIdx.z;             // b*H + h
  const int b = z >> 4, h = z & 15;
  const int t = threadIdx.x;
  const int lane = t & 63, wave = t >> 6;
  const int wm = (wave >> 1) * 32;      // QK: key half owned; PV: out-row(query) half
  const int wc = wave & 1;
  const int wn = wc * 32;               // QK: query half; PV: d half
  const int q = lane >> 4, l16 = lane & 15;
  const int srow = t >> 2, sc = (t & 3) * 8;

  const ushort* qz = qh + ((long)z << 16);
  const ushort* kz = kh + ((long)z << 16);
  const ushort* vz = vt + ((long)z << 16);
  const int q0 = blockIdx.x * 64;
  const float LOG2E = 1.44269504f;
  const float SC2   = 0.125f * LOG2E;
  const float MSC2  = -1e9f * LOG2E;

  // stage Q tile once (visible after first in-loop barrier pair)
  {
    const ushort* src = qz + (long)(q0 + srow) * 64 + sc;
    *(uint4*)(&qs[srow][sc])      = *(const uint4*)(src);
    *(uint4*)(&qs[srow][sc + 32]) = *(const uint4*)(src + 32);
  }

  float m2[2], lsum[2];                 // per owned query (tj)
  m2[0] = m2[1] = -1e30f; lsum[0] = lsum[1] = 0.f;

  // ---------------- pass 1: row max + sum (log2 domain) ----------------
  uint4 kv0, kv1; float mv;
  {
    const ushort* ksrc = kz + (long)srow * 64 + sc;
    kv0 = *(const uint4*)(ksrc); kv1 = *(const uint4*)(ksrc + 32);
    mv = (t < 64) ? mask[(b<<10) + t] * MSC2 : 0.f;
  }
  for (int s = 0; s < 16; ++s){
    __syncthreads();                    // prior strip's ks reads done
    *(uint4*)(&ks[srow][sc])      = kv0;
    *(uint4*)(&ks[srow][sc + 32]) = kv1;
    if (t < 64) msk[t] = mv;
    __syncthreads();
    if (s < 15){                        // T14: prefetch next strip under compute
      const ushort* ksrc = kz + (long)((s+1)*64 + srow) * 64 + sc;
      kv0 = *(const uint4*)(ksrc); kv1 = *(const uint4*)(ksrc + 32);
      if (t < 64) mv = mask[(b<<10) + (s+1)*64 + t] * MSC2;
    }

    f32x4 accs[2][2] = {};              // [key-tile][query-tile]
    #pragma unroll
    for (int kk=0; kk<2; ++kk){
      bf16x8 a0 = *(const bf16x8*)(&ks[wm      + l16][kk*32 + q*8]);
      bf16x8 a1 = *(const bf16x8*)(&ks[wm + 16 + l16][kk*32 + q*8]);
      bf16x8 b0 = *(const bf16x8*)(&qs[wn      + l16][kk*32 + q*8]);
      bf16x8 b1 = *(const bf16x8*)(&qs[wn + 16 + l16][kk*32 + q*8]);
      accs[0][0] = __builtin_amdgcn_mfma_f32_16x16x32_bf16(a0,b0,accs[0][0],0,0,0);
      accs[0][1] = __builtin_amdgcn_mfma_f32_16x16x32_bf16(a0,b1,accs[0][1],0,0,0);
      accs[1][0] = __builtin_amdgcn_mfma_f32_16x16x32_bf16(a1,b0,accs[1][0],0,0,0);
      accs[1][1] = __builtin_amdgcn_mfma_f32_16x16x32_bf16(a1,b1,accs[1][1],0,0,0);
    }
    // online update: per query tj, 8 new key-scores (ti x r)
    #pragma unroll
    for (int tj=0; tj<2; ++tj){
      float sv[8];
      #pragma unroll
      for (int ti=0; ti<2; ++ti)
      #pragma unroll
      for (int r=0; r<4; ++r){
        const int key = wm + ti*16 + q*4 + r;
        sv[ti*4+r] = accs[ti][tj][r]*SC2 + msk[key];
      }
      float mx01 = fmaxf(sv[0],sv[1]), mx23 = fmaxf(sv[2],sv[3]);
      float mx45 = fmaxf(sv[4],sv[5]), mx67 = fmaxf(sv[6],sv[7]);
      float mx = fmaxf(fmaxf(fmaxf(mx01,mx23), fmaxf(mx45,mx67)), m2[tj]);
      float e0 = fexp2(sv[0]-mx), e1 = fexp2(sv[1]-mx);
      float e2 = fexp2(sv[2]-mx), e3 = fexp2(sv[3]-mx);
      float e4 = fexp2(sv[4]-mx), e5 = fexp2(sv[5]-mx);
      float e6 = fexp2(sv[6]-mx), e7 = fexp2(sv[7]-mx);
      float add = ((e0+e1)+(e2+e3)) + ((e4+e5)+(e6+e7));
      lsum[tj] = lsum[tj]*fexp2(m2[tj]-mx) + add;
      m2[tj] = mx;
    }
  }

  // reduce across the 4 q-groups (same l16): xor 16, 32
  #pragma unroll
  for (int tj=0; tj<2; ++tj){
    float m = m2[tj], l = lsum[tj];
    #pragma unroll
    for (int off=16; off<=32; off<<=1){
      float om = __shfl_xor(m, off, 64);
      float ol = __shfl_xor(l, off, 64);
      float mn = fmaxf(m, om);
      l = l*fexp2(m-mn) + ol*fexp2(om-mn);
      m = mn;
    }
    m2[tj] = m; lsum[tj] = l;
  }
  // combine the two key-halves (wave>>1) per query
  if (lane < 16){
    #pragma unroll
    for (int tj=0; tj<2; ++tj){
      red_m[wave>>1][wn + tj*16 + l16] = m2[tj];
      red_l[wave>>1][wn + tj*16 + l16] = lsum[tj];
    }
  }
  __syncthreads();
  float m2f[2], li[2];
  #pragma unroll
  for (int tj=0; tj<2; ++tj){
    const int query = wn + tj*16 + l16;
    const float ma = red_m[0][query], mb = red_m[1][query];
    const float la = red_l[0][query], lb = red_l[1][query];
    const float mt = fmaxf(ma, mb);
    m2f[tj] = mt;
    li[tj]  = 1.0f / (la*fexp2(ma-mt) + lb*fexp2(mb-mt));
  }

  // ---------------- pass 2: attn write (float4) + PV ----------------
  f32x4 accp[2][2] = {};
  uint4 vv0, vv1;
  {
    const ushort* ksrc = kz + (long)srow * 64 + sc;
    kv0 = *(const uint4*)(ksrc); kv1 = *(const uint4*)(ksrc + 32);
    const ushort* vsrc = vz + (long)srow * 1024 + sc;
    vv0 = *(const uint4*)(vsrc); vv1 = *(const uint4*)(vsrc + 32);
    mv = (t < 64) ? mask[(b<<10) + t] * MSC2 : 0.f;
  }
  for (int s = 0; s < 16; ++s){
    const int k0 = s * 64;
    __syncthreads();                    // prior QK ks-reads + PV vs/ps-reads done
    *(uint4*)(&ks[srow][sc])      = kv0;
    *(uint4*)(&ks[srow][sc + 32]) = kv1;
    *(uint4*)(&vs[srow][sc])      = vv0;
    *(uint4*)(&vs[srow][sc + 32]) = vv1;
    if (t < 64) msk[t] = mv;
    __syncthreads();
    if (s < 15){
      const ushort* ksrc = kz + (long)(k0 + 64 + srow) * 64 + sc;
      kv0 = *(const uint4*)(ksrc); kv1 = *(const uint4*)(ksrc + 32);
      const ushort* vsrc = vz + (long)srow * 1024 + k0 + 64 + sc;
      vv0 = *(const uint4*)(vsrc); vv1 = *(const uint4*)(vsrc + 32);
      if (t < 64) mv = mask[(b<<10) + k0 + 64 + t] * MSC2;
    }

    f32x4 accs[2][2] = {};
    #pragma unroll
    for (int kk=0; kk<2; ++kk){
      bf16x8 a0 = *(const bf16x8*)(&ks[wm      + l16][kk*32 + q*8]);
      bf16x8 a1 = *(const bf16x8*)(&ks[wm + 16 + l16][kk*32 + q*8]);
      bf16x8 b0 = *(const bf16x8*)(&qs[wn      + l16][kk*32 + q*8]);
      bf16x8 b1 = *(const bf16x8*)(&qs[wn + 16 + l16][kk*32 + q*8]);
      accs[0][0] = __builtin_amdgcn_mfma_f32_16x16x32_bf16(a0,b0,accs[0][0],0,0,0);
      accs[0][1] = __builtin_amdgcn_mfma_f32_16x16x32_bf16(a0,b1,accs[0][1],0,0,0);
      accs[1][0] = __builtin_amdgcn_mfma_f32_16x16x32_bf16(a1,b0,accs[1][0],0,0,0);
      accs[1][1] = __builtin_amdgcn_mfma_f32_16x16x32_bf16(a1,b1,accs[1][1],0,0,0);
    }
    // p = exp2(s2 - m2f) * li ; 4 consecutive keys per (ti,tj) -> float4/b64 stores
    #pragma unroll
    for (int ti=0; ti<2; ++ti)
    #pragma unroll
    for (int tj=0; tj<2; ++tj){
      const int keyb  = wm + ti*16 + q*4;
      const int query = wn + tj*16 + l16;
      float4 pv;
      pv.x = fexp2(accs[ti][tj][0]*SC2 + msk[keyb+0] - m2f[tj]) * li[tj];
      pv.y = fexp2(accs[ti][tj][1]*SC2 + msk[keyb+1] - m2f[tj]) * li[tj];
      pv.z = fexp2(accs[ti][tj][2]*SC2 + msk[keyb+2] - m2f[tj]) * li[tj];
      pv.w = fexp2(accs[ti][tj][3]*SC2 + msk[keyb+3] - m2f[tj]) * li[tj];
      *(float4*)(attn_f + ((long)z<<20) + ((long)(q0+query)<<10) + k0 + keyb) = pv;
      ushort4 pb;
      pb.x = f2bf(pv.x); pb.y = f2bf(pv.y); pb.z = f2bf(pv.z); pb.w = f2bf(pv.w);
      *(ushort4*)(&ps[query][keyb]) = pb;
    }
    __syncthreads();
    // PV: out[query][d] ; A = ps rows (queries, wm half), B = vs rows (d, wn half)
    #pragma unroll
    for (int kk=0; kk<2; ++kk){
      bf16x8 a0 = *(const bf16x8*)(&ps[wm      + l16][kk*32 + q*8]);
      bf16x8 a1 = *(const bf16x8*)(&ps[wm + 16 + l16][kk*32 + q*8]);
      bf16x8 b0 = *(const bf16x8*)(&vs[wn      + l16][kk*32 + q*8]);
      bf16x8 b1 = *(const bf16x8*)(&vs[wn + 16 + l16][kk*32 + q*8]);
      accp[0][0] = __builtin_amdgcn_mfma_f32_16x16x32_bf16(a0,b0,accp[0][0],0,0,0);
      accp[0][1] = __builtin_amdgcn_mfma_f32_16x16x32_bf16(a0,b1,accp[0][1],0,0,0);
      accp[1][0] = __builtin_amdgcn_mfma_f32_16x16x32_bf16(a1,b0,accp[1][0],0,0,0);
      accp[1][1] = __builtin_amdgcn_mfma_f32_16x16x32_bf16(a1,b1,accp[1][1],0,0,0);
    }
  }

  // epilogue: rows = queries (wm half), cols = d (wn half)
  #pragma unroll
  for (int mi=0; mi<2; mi++)
  #pragma unroll
  for (int nj=0; nj<2; nj++)
  #pragma unroll
  for (int r=0; r<4; r++){
    const int row = q0 + wm + mi*16 + q*4 + r;
    const int d   = wn + nj*16 + l16;
    concat[(((long)(b<<10) + row)<<10) + (h<<6) + d] = f2bf(accp[mi][nj][r]);
  }
}

extern "C" void kernel_launch(void* const* d_in, const int* in_sizes, int n_in,
                              void* d_out, int out_size, void* d_ws, size_t ws_size,
                              hipStream_t stream)
{
  (void)in_sizes; (void)n_in; (void)out_size; (void)ws_size;
  const float* Q    = (const float*)d_in[0];
  const float* Kin  = (const float*)d_in[1];
  const float* V    = (const float*)d_in[2];
  const float* mask = (const float*)d_in[3];
  const float* Wq   = (const float*)d_in[4];
  const float* bq   = (const float*)d_in[5];
  const float* Wk   = (const float*)d_in[6];
  const float* bk   = (const float*)d_in[7];
  const float* Wv   = (const float*)d_in[8];
  const float* bv   = (const float*)d_in[9];
  const float* Wo   = (const float*)d_in[10];
  const float* bo   = (const float*)d_in[11];
  float* out    = (float*)d_out;
  float* attn_f = out + (long)BSD;

  // Workspace layout (ushort elements) — unchanged.
  ushort* ws     = (ushort*)d_ws;
  ushort* Xq     = ws;                 // bf16 Q input; reused as concat buffer later
  ushort* Xk     = Xq  + (long)BSD;
  ushort* Xv     = Xk  + (long)BSD;
  ushort* WqT    = Xv  + (long)BSD;
  ushort* WkT    = WqT + (long)DDn;
  ushort* WvT    = WkT + (long)DDn;
  ushort* WoT    = WvT + (long)DDn;
  ushort* qh     = WoT + (long)DDn;    // [b,h,s,64] bf16
  ushort* kh     = qh  + (long)BSD;
  ushort* vt     = kh  + (long)BSD;    // [b,h,64,s] bf16
  ushort* vh     = vt  + (long)BSD;    // temp [b,h,s,64]
  ushort* concat = Xq;                 // [b,s,D] bf16, reuse of Xq

  // 1. fp32 -> bf16 input converts
  cvt_bf16<<<dim3(BSD/4/256), 256, 0, stream>>>((const float4*)Q,   (ushort4*)Xq, BSD/4);
  cvt_bf16<<<dim3(BSD/4/256), 256, 0, stream>>>((const float4*)Kin, (ushort4*)Xk, BSD/4);
  cvt_bf16<<<dim3(BSD/4/256), 256, 0, stream>>>((const float4*)V,   (ushort4*)Xv, BSD/4);

  // 2. weight transposes (fp32 -> bf16 W^T)
  transpose_w<<<dim3(32,32), dim3(32,8), 0, stream>>>(Wq, WqT);
  transpose_w<<<dim3(32,32), dim3(32,8), 0, stream>>>(Wk, WkT);
  transpose_w<<<dim3(32,32), dim3(32,8), 0, stream>>>(Wv, WvT);
  transpose_w<<<dim3(32,32), dim3(32,8), 0, stream>>>(Wo, WoT);

  // 3. projections: [8192,1024] @ W^T -> head-split bf16 (m97-structure GEMM)
  gemm128<M_PROJ><<<dim3(64,8,1), 256, 0, stream>>>(Xq, WqT, nullptr, qh, bq);
  gemm128<M_PROJ><<<dim3(64,8,1), 256, 0, stream>>>(Xk, WkT, nullptr, kh, bk);
  gemm128<M_PROJ><<<dim3(64,8,1), 256, 0, stream>>>(Xv, WvT, nullptr, vh, bv);

  // 3b. v [bh,s,64] -> v^T [bh,64,s]
  transpose_v<<<dim3(16,128), dim3(64,8), 0, stream>>>(vh, vt);

  // 4-6 fused: scores -> softmax (fp32 attn out) -> PV (bf16 concat out)
  attn_fused<<<dim3(16,1,128), 256, 0, stream>>>(qh, kh, vt, mask, attn_f, concat);

  // 7. final: concat @ Wo + bo -> fp32 out
  gemm128<M_FINAL><<<dim3(64,8,1), 256, 0, stream>>>(concat, WoT, out, nullptr, bo);
}